// Round 1
// baseline (4869.239 us; speedup 1.0000x reference)
//
#include <hip/hip_runtime.h>

// DeltaNet chunkwise delta rule, fp32.
// Shapes: b=2, h=8, L=4096, d=128, chunk=32 -> 16 heads, 128 chunks/head.
// Phase 1 (prep): parallel over 2048 (head,chunk) tiles -> u, w, attn in ws.
// Phase 2 (scan): sequential over chunks; parallel over 16 heads x 8 col-groups
//                 (the recurrence is independent per v-column).

#define Bb 2
#define Hh 8
#define Ll 4096
#define Dd 128
#define Cc 32
#define NC (Ll / Cc)      // 128 chunks
#define BHn (Bb * Hh)     // 16 heads
#define COLS 16
#define GROUPS (Dd / COLS) // 8

// ---------------------------------------------------------------------------
// Kernel 1: per-(head,chunk) precompute.
//   kn = l2norm(k); qn = l2norm(q); vb = v*beta
//   A[i][j]   = beta_i * dot(kn_i, kn_j)
//   T = strict_lower(A) + I ; inv = T^-1 (unit lower triangular)
//   u = inv @ vb ; w = inv @ (kn*beta) ; attn = tril(qn @ kn^T)
// ---------------------------------------------------------------------------
__global__ __launch_bounds__(256) void prep_kernel(
    const float* __restrict__ q, const float* __restrict__ k,
    const float* __restrict__ v, const float* __restrict__ beta,
    float* __restrict__ wsU, float* __restrict__ wsW,
    float* __restrict__ wsAttn)
{
    __shared__ float sK[Cc][Dd];   // normalized k
    __shared__ float sQ[Cc][Dd];   // normalized q
    __shared__ float sV[Cc][Dd];   // v * beta
    __shared__ float sA[Cc][Cc];
    __shared__ float sInv[Cc][Cc];
    __shared__ float sBeta[Cc], sNormK[Cc], sNormQ[Cc];

    const int tid = threadIdx.x;
    const int blk = blockIdx.x;          // bh*NC + ch
    const int bh = blk / NC;
    const int ch = blk % NC;
    const size_t base = (size_t)(bh * Ll + ch * Cc) * Dd;

    const float4* gq = (const float4*)(q + base);
    const float4* gk = (const float4*)(k + base);
    const float4* gv = (const float4*)(v + base);
    for (int e = tid; e < Cc * Dd / 4; e += 256) {
        ((float4*)&sQ[0][0])[e] = gq[e];
        ((float4*)&sK[0][0])[e] = gk[e];
        ((float4*)&sV[0][0])[e] = gv[e];
    }
    if (tid < Cc) sBeta[tid] = beta[bh * Ll + ch * Cc + tid];
    __syncthreads();

    // row L2 norms (threads 0..31: k rows, 32..63: q rows)
    if (tid < Cc) {
        float s = 0.f;
        for (int x = 0; x < Dd; ++x) s += sK[tid][x] * sK[tid][x];
        sNormK[tid] = 1.0f / sqrtf(s);
    } else if (tid < 2 * Cc) {
        const int r = tid - Cc;
        float s = 0.f;
        for (int x = 0; x < Dd; ++x) s += sQ[r][x] * sQ[r][x];
        sNormQ[r] = 1.0f / sqrtf(s);
    }
    __syncthreads();

    for (int e = tid; e < Cc * Dd; e += 256) {
        const int r = e >> 7, c = e & 127;
        sK[r][c] *= sNormK[r];
        sQ[r][c] *= sNormQ[r];
        sV[r][c] *= sBeta[r];
    }
    __syncthreads();

    // A[i][j] = beta_i * dot(kn_i, kn_j)
    for (int e = tid; e < Cc * Cc; e += 256) {
        const int i = e >> 5, j = e & 31;
        float s = 0.f;
        for (int x = 0; x < Dd; ++x) s += sK[i][x] * sK[j][x];
        sA[i][j] = s * sBeta[i];
    }
    for (int e = tid; e < Cc * Cc; e += 256)
        sInv[e >> 5][e & 31] = ((e >> 5) == (e & 31)) ? 1.0f : 0.0f;
    __syncthreads();

    // forward substitution: inv[i][j] = -sum_{m=j}^{i-1} A[i][m]*inv[m][j]
    for (int i = 1; i < Cc; ++i) {
        if (tid < i) {
            const int j = tid;
            float s = 0.f;
            for (int m = j; m < i; ++m) s += sA[i][m] * sInv[m][j];
            sInv[i][j] = -s;
        }
        __syncthreads();
    }

    // u = inv @ vb ; w = inv @ (kn * beta)
    const size_t cbase = (size_t)blk * Cc * Dd;
    for (int e = tid; e < Cc * Dd; e += 256) {
        const int c = e >> 7, dd = e & 127;
        float su = 0.f, sw = 0.f;
        for (int f = 0; f <= c; ++f) {
            const float iv = sInv[c][f];
            su += iv * sV[f][dd];
            sw += iv * sBeta[f] * sK[f][dd];
        }
        wsU[cbase + e] = su;
        wsW[cbase + e] = sw;
    }

    // attn = tril(qn @ kn^T), diag included
    const size_t abase = (size_t)blk * Cc * Cc;
    for (int e = tid; e < Cc * Cc; e += 256) {
        const int i = e >> 5, j = e & 31;
        float s = 0.f;
        if (j <= i)
            for (int x = 0; x < Dd; ++x) s += sQ[i][x] * sK[j][x];
        wsAttn[abase + e] = s;
    }
}

// ---------------------------------------------------------------------------
// Kernel 2: sequential scan over chunks. Grid (16 heads, 8 col-groups).
// Each block owns a 128x16 slice of S (columns colBase..colBase+15).
// Per chunk:
//   u_adj = u - w @ S          (32 x 16)
//   o     = qn @ S + attn @ u_adj  -> global out
//   S    += kn^T @ u_adj
// ---------------------------------------------------------------------------
__global__ __launch_bounds__(256) void scan_kernel(
    const float* __restrict__ q, const float* __restrict__ k,
    const float* __restrict__ wsU, const float* __restrict__ wsW,
    const float* __restrict__ wsAttn, float* __restrict__ out)
{
    __shared__ float sW[Cc][Dd];      // 16 KB
    __shared__ float sQ[Cc][Dd];      // 16 KB (normalized in place)
    __shared__ float sK[Cc][Dd];      // 16 KB (normalized in place)
    __shared__ float sAttn[Cc][Cc];   // 4 KB
    __shared__ float sUadj[Cc][COLS]; // 2 KB
    __shared__ float sS[COLS][Dd];    // 8 KB, transposed: sS[col][kdim]
    __shared__ float sNormQ[Cc], sNormK[Cc];

    const int tid = threadIdx.x;
    const int bh = blockIdx.x;
    const int grp = blockIdx.y;
    const int colBase = grp * COLS;

    for (int e = tid; e < COLS * Dd; e += 256) ((float*)sS)[e] = 0.0f;

    for (int ch = 0; ch < NC; ++ch) {
        __syncthreads();  // protect sK/sW/sUadj reads of previous iter
        const size_t base  = (size_t)(bh * Ll + ch * Cc) * Dd;
        const size_t cbase = (size_t)(bh * NC + ch) * Cc * Dd;
        const size_t abase = (size_t)(bh * NC + ch) * Cc * Cc;

        const float4* gq = (const float4*)(q + base);
        const float4* gk = (const float4*)(k + base);
        const float4* gw = (const float4*)(wsW + cbase);
        const float4* ga = (const float4*)(wsAttn + abase);
        for (int e = tid; e < Cc * Dd / 4; e += 256) {
            ((float4*)&sQ[0][0])[e] = gq[e];
            ((float4*)&sK[0][0])[e] = gk[e];
            ((float4*)&sW[0][0])[e] = gw[e];
        }
        for (int e = tid; e < Cc * Cc / 4; e += 256)
            ((float4*)&sAttn[0][0])[e] = ga[e];

        // this block's u slice -> registers (2 values per thread)
        float ureg[(Cc * COLS) / 256];
        #pragma unroll
        for (int t = 0; t < (Cc * COLS) / 256; ++t) {
            const int e = tid + t * 256;
            const int c = e / COLS, col = e % COLS;
            ureg[t] = wsU[cbase + (size_t)c * Dd + colBase + col];
        }
        __syncthreads();

        // normalize q, k rows
        if (tid < Cc) {
            float s = 0.f;
            for (int x = 0; x < Dd; ++x) s += sQ[tid][x] * sQ[tid][x];
            sNormQ[tid] = 1.0f / sqrtf(s);
        } else if (tid < 2 * Cc) {
            const int r = tid - Cc;
            float s = 0.f;
            for (int x = 0; x < Dd; ++x) s += sK[r][x] * sK[r][x];
            sNormK[r] = 1.0f / sqrtf(s);
        }
        __syncthreads();
        for (int e = tid; e < Cc * Dd; e += 256) {
            const int r = e >> 7, c = e & 127;
            sQ[r][c] *= sNormQ[r];
            sK[r][c] *= sNormK[r];
        }
        __syncthreads();

        // u_adj = u - w @ S
        #pragma unroll
        for (int t = 0; t < (Cc * COLS) / 256; ++t) {
            const int e = tid + t * 256;
            const int c = e / COLS, col = e % COLS;
            float acc = ureg[t];
            const float4* wrow = (const float4*)&sW[c][0];
            const float4* srow = (const float4*)&sS[col][0];
            for (int k4 = 0; k4 < Dd / 4; ++k4) {
                const float4 wv = wrow[k4], sv = srow[k4];
                acc -= wv.x * sv.x + wv.y * sv.y + wv.z * sv.z + wv.w * sv.w;
            }
            sUadj[c][col] = acc;
        }
        __syncthreads();

        // o = qn @ S + attn @ u_adj  -> global
        #pragma unroll
        for (int t = 0; t < (Cc * COLS) / 256; ++t) {
            const int e = tid + t * 256;
            const int c = e / COLS, col = e % COLS;
            float acc = 0.f;
            const float4* qrow = (const float4*)&sQ[c][0];
            const float4* srow = (const float4*)&sS[col][0];
            for (int k4 = 0; k4 < Dd / 4; ++k4) {
                const float4 qv = qrow[k4], sv = srow[k4];
                acc += qv.x * sv.x + qv.y * sv.y + qv.z * sv.z + qv.w * sv.w;
            }
            for (int f = 0; f < Cc; ++f) acc += sAttn[c][f] * sUadj[f][col];
            out[base + (size_t)c * Dd + colBase + col] = acc;
        }
        __syncthreads();  // all reads of sS done before update

        // S += kn^T @ u_adj  (each thread: 8 k-dims of one column)
        for (int e = tid; e < (Dd * COLS) / 8; e += 256) {
            const int col = e % COLS;
            const int k0 = (e / COLS) * 8;
            float acc[8];
            #pragma unroll
            for (int i = 0; i < 8; ++i) acc[i] = sS[col][k0 + i];
            for (int c = 0; c < Cc; ++c) {
                const float ua = sUadj[c][col];
                const float4 ka = ((const float4*)&sK[c][0])[k0 / 4];
                const float4 kb = ((const float4*)&sK[c][0])[k0 / 4 + 1];
                acc[0] += ka.x * ua; acc[1] += ka.y * ua;
                acc[2] += ka.z * ua; acc[3] += ka.w * ua;
                acc[4] += kb.x * ua; acc[5] += kb.y * ua;
                acc[6] += kb.z * ua; acc[7] += kb.w * ua;
            }
            #pragma unroll
            for (int i = 0; i < 8; ++i) sS[col][k0 + i] = acc[i];
        }
    }
    __syncthreads();

    // S_final -> d_out tail
    const size_t soff = (size_t)Bb * Hh * Ll * Dd;
    for (int e = tid; e < Dd * COLS; e += 256) {
        const int kk = e / COLS, col = e % COLS;
        out[soff + (size_t)bh * Dd * Dd + (size_t)kk * Dd + colBase + col] =
            sS[col][kk];
    }
}

extern "C" void kernel_launch(void* const* d_in, const int* in_sizes, int n_in,
                              void* d_out, int out_size, void* d_ws,
                              size_t ws_size, hipStream_t stream) {
    const float* q    = (const float*)d_in[0];
    const float* k    = (const float*)d_in[1];
    const float* v    = (const float*)d_in[2];
    const float* beta = (const float*)d_in[3];
    float* out = (float*)d_out;

    float* ws = (float*)d_ws;
    float* wsU = ws;                                   // 16*4096*128 floats
    float* wsW = wsU + (size_t)BHn * Ll * Dd;          // 16*4096*128 floats
    float* wsAttn = wsW + (size_t)BHn * Ll * Dd;       // 16*128*32*32 floats

    prep_kernel<<<dim3(BHn * NC), 256, 0, stream>>>(q, k, v, beta,
                                                    wsU, wsW, wsAttn);
    scan_kernel<<<dim3(BHn, GROUPS), 256, 0, stream>>>(q, k, wsU, wsW,
                                                       wsAttn, out);
}

// Round 2
// 855.174 us; speedup vs baseline: 5.6939x; 5.6939x over previous
//
#include <hip/hip_runtime.h>

// DeltaNet chunkwise delta rule, fp32. b=2,h=8,L=4096,d=128,chunk=32.
// R2: LDS rows padded (stride 132 / 36) to kill bank conflicts (R1: 1.08e9
// conflict cycles = 78% of runtime). Norms computed once in prep and passed
// via ws (scan folds the reciprocal scalars into o and the S-update).
// COLS=8 -> 256 scan blocks (1/CU) instead of 128.

#define Bb 2
#define Hh 8
#define Ll 4096
#define Dd 128
#define DP (Dd + 4)        // padded row stride: bank = (4*row + word) % 32
#define Cc 32
#define CP (Cc + 4)        // 36: 16B-aligned rows, bank = (4*row + word) % 32
#define NC (Ll / Cc)       // 128 chunks
#define BHn (Bb * Hh)      // 16 heads
#define COLS 8
#define GROUPS (Dd / COLS) // 16 -> 256 scan blocks

// ---------------------------------------------------------------------------
// Kernel 1: per-(head,chunk) precompute.  2048 blocks x 256.
//   rnk/rnq = 1/||k||, 1/||q|| (stored to ws); kn,qn normalized in LDS
//   A = beta_i * kn_i.kn_j ; inv = (strict_lower(A)+I)^-1
//   u = inv @ (v*beta) ; w = inv @ (kn*beta) ; attn = tril(qn @ kn^T)
// ---------------------------------------------------------------------------
__global__ __launch_bounds__(256) void prep_kernel(
    const float* __restrict__ q, const float* __restrict__ k,
    const float* __restrict__ v, const float* __restrict__ beta,
    float* __restrict__ wsU, float* __restrict__ wsW,
    float* __restrict__ wsAttn, float* __restrict__ wsNq,
    float* __restrict__ wsNk)
{
    __shared__ float sK[Cc][DP];
    __shared__ float sQ[Cc][DP];
    __shared__ float sV[Cc][DP];
    __shared__ float sA[Cc][CP];
    __shared__ float sInv[Cc][CP];
    __shared__ float sBeta[Cc], sNk[Cc], sNq[Cc];

    const int tid = threadIdx.x;
    const int blk = blockIdx.x;          // bh*NC + ch
    const int bh = blk / NC;
    const int ch = blk % NC;
    const size_t base = (size_t)(bh * Ll + ch * Cc) * Dd;

    // stage q,k,v into padded rows (lanes sweep contiguous words: no conflict)
    for (int e = tid; e < Cc * Dd / 4; e += 256) {
        const int r = e >> 5, c4 = e & 31;
        ((float4*)&sQ[r][0])[c4] = ((const float4*)(q + base))[e];
        ((float4*)&sK[r][0])[c4] = ((const float4*)(k + base))[e];
        ((float4*)&sV[r][0])[c4] = ((const float4*)(v + base))[e];
    }
    if (tid < Cc) sBeta[tid] = beta[bh * Ll + ch * Cc + tid];
    __syncthreads();

    // row norms: 4 lanes per row, rows 0..31 = k, 32..63 = q
    {
        const int row = tid >> 2, part = tid & 3;
        const float* src = (row < Cc) ? &sK[row][0] : &sQ[row - Cc][0];
        float s = 0.f;
        #pragma unroll
        for (int j = 0; j < 8; ++j) {
            const float4 t = ((const float4*)src)[part + j * 4];
            s += t.x * t.x + t.y * t.y + t.z * t.z + t.w * t.w;
        }
        s += __shfl_xor(s, 1);
        s += __shfl_xor(s, 2);
        if (part == 0) {
            const float r = 1.0f / sqrtf(s);
            if (row < Cc) sNk[row] = r; else sNq[row - Cc] = r;
        }
    }
    __syncthreads();

    if (tid < Cc) {
        wsNk[bh * Ll + ch * Cc + tid] = sNk[tid];
        wsNq[bh * Ll + ch * Cc + tid] = sNq[tid];
    }
    // normalize k,q and scale v by beta (in place, conflict-free sweep)
    for (int e = tid; e < Cc * Dd / 4; e += 256) {
        const int r = e >> 5, c4 = e & 31;
        float4 kk = ((float4*)&sK[r][0])[c4];
        float4 qq = ((float4*)&sQ[r][0])[c4];
        float4 vv = ((float4*)&sV[r][0])[c4];
        const float nk = sNk[r], nq = sNq[r], bb = sBeta[r];
        kk.x *= nk; kk.y *= nk; kk.z *= nk; kk.w *= nk;
        qq.x *= nq; qq.y *= nq; qq.z *= nq; qq.w *= nq;
        vv.x *= bb; vv.y *= bb; vv.z *= bb; vv.w *= bb;
        ((float4*)&sK[r][0])[c4] = kk;
        ((float4*)&sQ[r][0])[c4] = qq;
        ((float4*)&sV[r][0])[c4] = vv;
    }
    __syncthreads();

    // A[i][j] = beta_i * dot(kn_i, kn_j); sInv = I
    for (int e = tid; e < Cc * Cc; e += 256) {
        const int i = e >> 5, j = e & 31;
        const float4* ri = (const float4*)&sK[i][0];
        const float4* rj = (const float4*)&sK[j][0];
        float s = 0.f;
        for (int x = 0; x < Dd / 4; ++x) {
            const float4 a = ri[x], b = rj[x];
            s += a.x * b.x + a.y * b.y + a.z * b.z + a.w * b.w;
        }
        sA[i][j] = s * sBeta[i];
        sInv[i][j] = (i == j) ? 1.0f : 0.0f;
    }
    __syncthreads();

    // forward substitution (unit lower triangular inverse)
    for (int i = 1; i < Cc; ++i) {
        if (tid < i) {
            const int j = tid;
            float s = 0.f;
            for (int m = j; m < i; ++m) s += sA[i][m] * sInv[m][j];
            sInv[i][j] = -s;
        }
        __syncthreads();
    }

    // u = inv @ (v*beta) ; w = inv @ (kn*beta)
    const size_t cbase = (size_t)blk * Cc * Dd;
    for (int e = tid; e < Cc * Dd; e += 256) {
        const int c = e >> 7, dd = e & 127;
        float su = 0.f, sw = 0.f;
        for (int f = 0; f <= c; ++f) {
            const float iv = sInv[c][f];
            su += iv * sV[f][dd];
            sw += iv * sBeta[f] * sK[f][dd];
        }
        wsU[cbase + e] = su;
        wsW[cbase + e] = sw;
    }

    // attn = tril(qn @ kn^T)
    const size_t abase = (size_t)blk * Cc * Cc;
    for (int e = tid; e < Cc * Cc; e += 256) {
        const int i = e >> 5, j = e & 31;
        float s = 0.f;
        if (j <= i) {
            const float4* ri = (const float4*)&sQ[i][0];
            const float4* rj = (const float4*)&sK[j][0];
            for (int x = 0; x < Dd / 4; ++x) {
                const float4 a = ri[x], b = rj[x];
                s += a.x * b.x + a.y * b.y + a.z * b.z + a.w * b.w;
            }
        }
        wsAttn[abase + e] = s;
    }
}

// ---------------------------------------------------------------------------
// Kernel 2: sequential scan over 128 chunks. Grid (16 heads, 16 col-groups).
// Each block owns a 128x8 slice of S (v-columns are independent).
// Per chunk: u_adj = u - w@S ; o = (q@S)*rq + attn@u_adj ; S += (k*rk)^T@u_adj
// ---------------------------------------------------------------------------
__global__ __launch_bounds__(256) void scan_kernel(
    const float* __restrict__ q, const float* __restrict__ k,
    const float* __restrict__ wsU, const float* __restrict__ wsW,
    const float* __restrict__ wsAttn, const float* __restrict__ wsNq,
    const float* __restrict__ wsNk, float* __restrict__ out)
{
    __shared__ float sW[Cc][DP];      // w
    __shared__ float sQ[Cc][DP];      // raw q (norm folded as scalar)
    __shared__ float sK[Cc][DP];      // raw k (norm folded as scalar)
    __shared__ float sAttn[Cc][CP];
    __shared__ float sUadj[Cc][COLS];
    __shared__ float sS[COLS][DP];    // S^T slice: sS[col][kdim]
    __shared__ float sNq[Cc], sNk[Cc];

    const int tid = threadIdx.x;
    const int bh = blockIdx.x;
    const int colBase = blockIdx.y * COLS;

    for (int e = tid; e < COLS * DP; e += 256) ((float*)sS)[e] = 0.0f;

    const int c8 = tid >> 3, col8 = tid & 7;   // u_adj / o mapping

    for (int ch = 0; ch < NC; ++ch) {
        __syncthreads();   // prev-iter readers of sK/sW/sUadj done
        const size_t base  = (size_t)(bh * Ll + ch * Cc) * Dd;
        const size_t cbase = (size_t)(bh * NC + ch) * Cc * Dd;
        const size_t abase = (size_t)(bh * NC + ch) * Cc * Cc;

        for (int e = tid; e < Cc * Dd / 4; e += 256) {
            const int r = e >> 5, c4 = e & 31;
            ((float4*)&sQ[r][0])[c4] = ((const float4*)(q + base))[e];
            ((float4*)&sK[r][0])[c4] = ((const float4*)(k + base))[e];
            ((float4*)&sW[r][0])[c4] = ((const float4*)(wsW + cbase))[e];
        }
        if (tid < Cc * Cc / 4) {
            const int i = tid >> 3, j4 = tid & 7;
            ((float4*)&sAttn[i][0])[j4] = ((const float4*)(wsAttn + abase))[tid];
        }
        if (tid < Cc) {
            sNq[tid] = wsNq[bh * Ll + ch * Cc + tid];
            sNk[tid] = wsNk[bh * Ll + ch * Cc + tid];
        }
        const float ureg = wsU[cbase + (size_t)c8 * Dd + colBase + col8];
        __syncthreads();

        // u_adj = u - w @ S   (one 32x8 element per thread)
        {
            float acc = ureg;
            const float4* wrow = (const float4*)&sW[c8][0];
            const float4* srow = (const float4*)&sS[col8][0];
            #pragma unroll
            for (int k4 = 0; k4 < Dd / 4; ++k4) {
                const float4 wv = wrow[k4], sv = srow[k4];
                acc -= wv.x * sv.x + wv.y * sv.y + wv.z * sv.z + wv.w * sv.w;
            }
            sUadj[c8][col8] = acc;
        }
        __syncthreads();

        // o = (q @ S) * rq + attn @ u_adj
        {
            float accq = 0.f;
            const float4* qrow = (const float4*)&sQ[c8][0];
            const float4* srow = (const float4*)&sS[col8][0];
            #pragma unroll
            for (int k4 = 0; k4 < Dd / 4; ++k4) {
                const float4 qv = qrow[k4], sv = srow[k4];
                accq += qv.x * sv.x + qv.y * sv.y + qv.z * sv.z + qv.w * sv.w;
            }
            float acc = accq * sNq[c8];
            #pragma unroll
            for (int f = 0; f < Cc; ++f) acc += sAttn[c8][f] * sUadj[f][col8];
            out[base + (size_t)c8 * Dd + colBase + col8] = acc;
        }
        __syncthreads();   // all reads of sS/sUadj done before S update

        // S += (k * rk)^T @ u_adj  (thread: one col, 4 consecutive k-dims)
        {
            const int col = tid >> 5;
            const int k0 = (tid & 31) * 4;
            float4 acc = *(float4*)&sS[col][k0];
            #pragma unroll
            for (int c = 0; c < Cc; ++c) {
                const float ua = sUadj[c][col] * sNk[c];
                const float4 ka = *(const float4*)&sK[c][k0];
                acc.x += ka.x * ua; acc.y += ka.y * ua;
                acc.z += ka.z * ua; acc.w += ka.w * ua;
            }
            *(float4*)&sS[col][k0] = acc;
        }
    }
    __syncthreads();

    // S_final -> d_out tail
    const size_t soff = (size_t)Bb * Hh * Ll * Dd;
    for (int e = tid; e < Dd * COLS; e += 256) {
        const int kk = e >> 3, col = e & 7;
        out[soff + (size_t)bh * Dd * Dd + (size_t)kk * Dd + colBase + col] =
            sS[col][kk];
    }
}

extern "C" void kernel_launch(void* const* d_in, const int* in_sizes, int n_in,
                              void* d_out, int out_size, void* d_ws,
                              size_t ws_size, hipStream_t stream) {
    const float* q    = (const float*)d_in[0];
    const float* k    = (const float*)d_in[1];
    const float* v    = (const float*)d_in[2];
    const float* beta = (const float*)d_in[3];
    float* out = (float*)d_out;

    float* ws = (float*)d_ws;
    float* wsU    = ws;                                  // 16*4096*128
    float* wsW    = wsU + (size_t)BHn * Ll * Dd;         // 16*4096*128
    float* wsAttn = wsW + (size_t)BHn * Ll * Dd;         // 16*128*1024
    float* wsNq   = wsAttn + (size_t)BHn * NC * Cc * Cc; // 16*4096
    float* wsNk   = wsNq + (size_t)BHn * Ll;             // 16*4096

    prep_kernel<<<dim3(BHn * NC), 256, 0, stream>>>(q, k, v, beta, wsU, wsW,
                                                    wsAttn, wsNq, wsNk);
    scan_kernel<<<dim3(BHn, GROUPS), 256, 0, stream>>>(q, k, wsU, wsW, wsAttn,
                                                       wsNq, wsNk, out);
}

// Round 3
// 601.638 us; speedup vs baseline: 8.0933x; 1.4214x over previous
//
#include <hip/hip_runtime.h>

// DeltaNet chunkwise delta rule. b=2,h=8,L=4096,d=128,chunk=32.
// R3: scan rewritten as single-wave-per-chain MFMA (bf16 in, fp32 acc).
//   - 64 waves total: 16 heads x 4 col-groups (W=32 v-columns each).
//   - S (128xW) lives in four 32x32 fp32 MFMA accumulator tiles; never in LDS.
//   - Per chunk: u_adj = u - w@S ; o = qn@S + attn@u_adj ; S += kn^T @ u_adj
//     -> 26 v_mfma_f32_32x32x16_bf16 per wave per chunk, no __syncthreads.
//   - S/u_adj C-layout -> B-operand conversion: 4 shfl_xor(.,32) per K-step.
//     Verified layouts: C/D col=lane&31, row=(reg&3)+8*(reg>>2)+4*(lane>>5);
//     A[m=lane&31][k=8*(lane>>5)+j]; B[k=8*(lane>>5)+j][n=lane&31].
// Prep additionally emits bf16 operands: wsWb = -w, wsKtb = kn^T, wsAttnb.
// ws layout total 71.6 MB (<= 72.5 MB proven safe in R2).

#define Bb 2
#define Hh 8
#define Ll 4096
#define Dd 128
#define DP (Dd + 4)
#define Cc 32
#define CP (Cc + 4)
#define NC (Ll / Cc)       // 128 chunks
#define BHn (Bb * Hh)      // 16 heads

typedef float  f32x16 __attribute__((ext_vector_type(16)));
typedef short  bf16x8 __attribute__((ext_vector_type(8)));

__device__ __forceinline__ short f2bf(float x) {
    union { float f; unsigned u; } a; a.f = x;
    const unsigned r = a.u + 0x7FFFu + ((a.u >> 16) & 1u);  // RNE
    return (short)(r >> 16);
}

// ---------------------------------------------------------------------------
// Kernel 1: per-(head,chunk) precompute. 2048 blocks x 256. (R2 body; outputs
// now: wsU fp32, wsNq fp32, wsWb=-w bf16, wsKtb=kn^T bf16, wsAttnb bf16.)
// ---------------------------------------------------------------------------
__global__ __launch_bounds__(256) void prep_kernel(
    const float* __restrict__ q, const float* __restrict__ k,
    const float* __restrict__ v, const float* __restrict__ beta,
    float* __restrict__ wsU, float* __restrict__ wsNq,
    short* __restrict__ wsWb, short* __restrict__ wsKtb,
    short* __restrict__ wsAttnb)
{
    __shared__ float sK[Cc][DP];
    __shared__ float sQ[Cc][DP];
    __shared__ float sV[Cc][DP];
    __shared__ float sA[Cc][CP];
    __shared__ float sInv[Cc][CP];
    __shared__ float sBeta[Cc], sNk[Cc], sNq[Cc];

    const int tid = threadIdx.x;
    const int blk = blockIdx.x;          // bh*NC + ch
    const int bh = blk / NC;
    const int ch = blk % NC;
    const size_t base = (size_t)(bh * Ll + ch * Cc) * Dd;

    for (int e = tid; e < Cc * Dd / 4; e += 256) {
        const int r = e >> 5, c4 = e & 31;
        ((float4*)&sQ[r][0])[c4] = ((const float4*)(q + base))[e];
        ((float4*)&sK[r][0])[c4] = ((const float4*)(k + base))[e];
        ((float4*)&sV[r][0])[c4] = ((const float4*)(v + base))[e];
    }
    if (tid < Cc) sBeta[tid] = beta[bh * Ll + ch * Cc + tid];
    __syncthreads();

    // row norms: 4 lanes per row, rows 0..31 = k, 32..63 = q
    {
        const int row = tid >> 2, part = tid & 3;
        const float* src = (row < Cc) ? &sK[row][0] : &sQ[row - Cc][0];
        float s = 0.f;
        #pragma unroll
        for (int j = 0; j < 8; ++j) {
            const float4 t = ((const float4*)src)[part + j * 4];
            s += t.x * t.x + t.y * t.y + t.z * t.z + t.w * t.w;
        }
        s += __shfl_xor(s, 1);
        s += __shfl_xor(s, 2);
        if (part == 0) {
            const float r = 1.0f / sqrtf(s);
            if (row < Cc) sNk[row] = r; else sNq[row - Cc] = r;
        }
    }
    __syncthreads();

    if (tid < Cc) wsNq[bh * Ll + ch * Cc + tid] = sNq[tid];

    for (int e = tid; e < Cc * Dd / 4; e += 256) {
        const int r = e >> 5, c4 = e & 31;
        float4 kk = ((float4*)&sK[r][0])[c4];
        float4 qq = ((float4*)&sQ[r][0])[c4];
        float4 vv = ((float4*)&sV[r][0])[c4];
        const float nk = sNk[r], nq = sNq[r], bb = sBeta[r];
        kk.x *= nk; kk.y *= nk; kk.z *= nk; kk.w *= nk;
        qq.x *= nq; qq.y *= nq; qq.z *= nq; qq.w *= nq;
        vv.x *= bb; vv.y *= bb; vv.z *= bb; vv.w *= bb;
        ((float4*)&sK[r][0])[c4] = kk;
        ((float4*)&sQ[r][0])[c4] = qq;
        ((float4*)&sV[r][0])[c4] = vv;
    }
    __syncthreads();

    // A[i][j] = beta_i * dot(kn_i, kn_j); sInv = I
    for (int e = tid; e < Cc * Cc; e += 256) {
        const int i = e >> 5, j = e & 31;
        const float4* ri = (const float4*)&sK[i][0];
        const float4* rj = (const float4*)&sK[j][0];
        float s = 0.f;
        for (int x = 0; x < Dd / 4; ++x) {
            const float4 a = ri[x], b = rj[x];
            s += a.x * b.x + a.y * b.y + a.z * b.z + a.w * b.w;
        }
        sA[i][j] = s * sBeta[i];
        sInv[i][j] = (i == j) ? 1.0f : 0.0f;
    }
    __syncthreads();

    // forward substitution (unit lower triangular inverse)
    for (int i = 1; i < Cc; ++i) {
        if (tid < i) {
            const int j = tid;
            float s = 0.f;
            for (int m = j; m < i; ++m) s += sA[i][m] * sInv[m][j];
            sInv[i][j] = -s;
        }
        __syncthreads();
    }

    // u = inv @ (v*beta) fp32 ; wsWb = -(inv @ (kn*beta)) bf16
    const size_t cbase = (size_t)blk * Cc * Dd;
    for (int e = tid; e < Cc * Dd; e += 256) {
        const int c = e >> 7, dd = e & 127;
        float su = 0.f, sw = 0.f;
        for (int f = 0; f <= c; ++f) {
            const float iv = sInv[c][f];
            su += iv * sV[f][dd];
            sw += iv * sBeta[f] * sK[f][dd];
        }
        wsU[cbase + e] = su;
        wsWb[cbase + e] = f2bf(-sw);
    }

    // wsKtb[dd][c] = kn[c][dd]  (bf16, transposed for S-update A-operand)
    for (int e = tid; e < Cc * Dd; e += 256) {
        const int dd = e >> 5, cc = e & 31;
        wsKtb[cbase + e] = f2bf(sK[cc][dd]);
    }

    // attn = tril(qn @ kn^T)  (bf16)
    const size_t abase = (size_t)blk * Cc * Cc;
    for (int e = tid; e < Cc * Cc; e += 256) {
        const int i = e >> 5, j = e & 31;
        float s = 0.f;
        if (j <= i) {
            const float4* ri = (const float4*)&sQ[i][0];
            const float4* rj = (const float4*)&sK[j][0];
            for (int x = 0; x < Dd / 4; ++x) {
                const float4 a = ri[x], b = rj[x];
                s += a.x * b.x + a.y * b.y + a.z * b.z + a.w * b.w;
            }
        }
        wsAttnb[abase + e] = f2bf(s);
    }
}

// ---------------------------------------------------------------------------
// Kernel 2: MFMA scan. Grid (16 heads, 4 col-groups) x 64 threads (1 wave).
// ---------------------------------------------------------------------------
__global__ __launch_bounds__(64, 1) void scan_kernel(
    const float* __restrict__ q, const float* __restrict__ wsU,
    const short* __restrict__ wsWb, const short* __restrict__ wsKtb,
    const short* __restrict__ wsAttnb, const float* __restrict__ wsNq,
    float* __restrict__ out)
{
    const int lane = threadIdx.x;
    const int h = lane >> 5;       // wave half
    const int c = lane & 31;
    const int bh = blockIdx.x;
    const int colBase = blockIdx.y * 32;

    f32x16 S0, S1, S2, S3;
    #pragma unroll
    for (int r = 0; r < 16; ++r) { S0[r]=0.f; S1[r]=0.f; S2[r]=0.f; S3[r]=0.f; }

    for (int ch = 0; ch < NC; ++ch) {
        const size_t cb = (size_t)(bh * NC + ch) * (Cc * Dd);
        const size_t ab = (size_t)(bh * NC + ch) * (Cc * Cc);
        const size_t qb = (size_t)(bh * Ll + ch * Cc) * Dd;

        // ---------------- loads (bf16 A-frags + fp32 u slice) --------------
        const float rq = wsNq[bh * Ll + ch * Cc + c];
        bf16x8 wA[8], kA[8], atA[2], qa[8];
        #pragma unroll
        for (int ks = 0; ks < 8; ++ks) {
            wA[ks] = ((const bf16x8*)(wsWb + cb))[c * 16 + 2 * ks + h];
            const float4 a = ((const float4*)(q + qb))[c * 32 + 4 * ks + 2 * h];
            const float4 b = ((const float4*)(q + qb))[c * 32 + 4 * ks + 2 * h + 1];
            qa[ks][0] = f2bf(a.x * rq); qa[ks][1] = f2bf(a.y * rq);
            qa[ks][2] = f2bf(a.z * rq); qa[ks][3] = f2bf(a.w * rq);
            qa[ks][4] = f2bf(b.x * rq); qa[ks][5] = f2bf(b.y * rq);
            qa[ks][6] = f2bf(b.z * rq); qa[ks][7] = f2bf(b.w * rq);
        }
        #pragma unroll
        for (int t = 0; t < 4; ++t)
            #pragma unroll
            for (int m = 0; m < 2; ++m)
                kA[t * 2 + m] =
                    ((const bf16x8*)(wsKtb + cb))[(32 * t + c) * 4 + 2 * m + h];
        #pragma unroll
        for (int m = 0; m < 2; ++m)
            atA[m] = ((const bf16x8*)(wsAttnb + ab))[c * 4 + 2 * m + h];

        f32x16 U, O;
        #pragma unroll
        for (int r = 0; r < 16; ++r) {
            const int row = (r & 3) + 8 * (r >> 2) + 4 * h;
            U[r] = wsU[cb + (size_t)row * Dd + colBase + c];
            O[r] = 0.f;
        }

        // -------- main K loop: U -= w@S ; O += qn@S (8 K-steps of 16) ------
        #pragma unroll
        for (int ks = 0; ks < 8; ++ks) {
            const f32x16& T = (ks < 2) ? S0 : (ks < 4) ? S1 : (ks < 6) ? S2 : S3;
            const int m = ks & 1;
            // C-layout -> B-operand: lane needs S[16ks+8h+j][colBase+c].
            bf16x8 sB;
            #pragma unroll
            for (int i = 0; i < 4; ++i) {
                const float A = T[8 * m + i];
                const float B = T[8 * m + 4 + i];
                const float z = h ? A : B;          // value my partner needs
                const float rr = __shfl_xor(z, 32); // partner's z
                sB[i]     = f2bf(h ? rr : A);
                sB[4 + i] = f2bf(h ? B : rr);
            }
            U = __builtin_amdgcn_mfma_f32_32x32x16_bf16(wA[ks], sB, U, 0, 0, 0);
            O = __builtin_amdgcn_mfma_f32_32x32x16_bf16(qa[ks], sB, O, 0, 0, 0);
        }

        // -------- u_adj (=U) -> B-frags for attn@u_adj and S-update --------
        bf16x8 uB[2];
        #pragma unroll
        for (int m = 0; m < 2; ++m) {
            #pragma unroll
            for (int i = 0; i < 4; ++i) {
                const float A = U[8 * m + i];
                const float B = U[8 * m + 4 + i];
                const float z = h ? A : B;
                const float rr = __shfl_xor(z, 32);
                uB[m][i]     = f2bf(h ? rr : A);
                uB[m][4 + i] = f2bf(h ? B : rr);
            }
        }
        O = __builtin_amdgcn_mfma_f32_32x32x16_bf16(atA[0], uB[0], O, 0, 0, 0);
        O = __builtin_amdgcn_mfma_f32_32x32x16_bf16(atA[1], uB[1], O, 0, 0, 0);

        #pragma unroll
        for (int r = 0; r < 16; ++r) {
            const int row = (r & 3) + 8 * (r >> 2) + 4 * h;
            out[qb + (size_t)row * Dd + colBase + c] = O[r];
        }

        // ------------------ S += kn^T @ u_adj ------------------------------
        S0 = __builtin_amdgcn_mfma_f32_32x32x16_bf16(kA[0], uB[0], S0, 0, 0, 0);
        S0 = __builtin_amdgcn_mfma_f32_32x32x16_bf16(kA[1], uB[1], S0, 0, 0, 0);
        S1 = __builtin_amdgcn_mfma_f32_32x32x16_bf16(kA[2], uB[0], S1, 0, 0, 0);
        S1 = __builtin_amdgcn_mfma_f32_32x32x16_bf16(kA[3], uB[1], S1, 0, 0, 0);
        S2 = __builtin_amdgcn_mfma_f32_32x32x16_bf16(kA[4], uB[0], S2, 0, 0, 0);
        S2 = __builtin_amdgcn_mfma_f32_32x32x16_bf16(kA[5], uB[1], S2, 0, 0, 0);
        S3 = __builtin_amdgcn_mfma_f32_32x32x16_bf16(kA[6], uB[0], S3, 0, 0, 0);
        S3 = __builtin_amdgcn_mfma_f32_32x32x16_bf16(kA[7], uB[1], S3, 0, 0, 0);
    }

    // S_final -> d_out tail
    const size_t soff = (size_t)Bb * Hh * Ll * Dd;
    #pragma unroll
    for (int t = 0; t < 4; ++t) {
        const f32x16& T = (t == 0) ? S0 : (t == 1) ? S1 : (t == 2) ? S2 : S3;
        #pragma unroll
        for (int r = 0; r < 16; ++r) {
            const int row = 32 * t + (r & 3) + 8 * (r >> 2) + 4 * h;
            out[soff + (size_t)bh * Dd * Dd + (size_t)row * Dd + colBase + c] =
                T[r];
        }
    }
}

extern "C" void kernel_launch(void* const* d_in, const int* in_sizes, int n_in,
                              void* d_out, int out_size, void* d_ws,
                              size_t ws_size, hipStream_t stream) {
    const float* q    = (const float*)d_in[0];
    const float* k    = (const float*)d_in[1];
    const float* v    = (const float*)d_in[2];
    const float* beta = (const float*)d_in[3];
    float* out = (float*)d_out;

    const size_t nQK = (size_t)BHn * Ll * Dd;   // 8,388,608 elements
    float* wsU    = (float*)d_ws;               // fp32, 32 MB
    float* wsNq   = wsU + nQK;                  // fp32, 0.25 MB
    short* wsWb   = (short*)(wsNq + (size_t)BHn * Ll);  // bf16, 16 MB
    short* wsKtb  = wsWb + nQK;                 // bf16, 16 MB
    short* wsAttnb = wsKtb + nQK;               // bf16, 4 MB   (total 71.6 MB)

    prep_kernel<<<dim3(BHn * NC), 256, 0, stream>>>(q, k, v, beta, wsU, wsNq,
                                                    wsWb, wsKtb, wsAttnb);
    scan_kernel<<<dim3(BHn, 4), 64, 0, stream>>>(q, wsU, wsWb, wsKtb, wsAttnb,
                                                 wsNq, out);
}

// Round 4
// 512.983 us; speedup vs baseline: 9.4920x; 1.1728x over previous
//
#include <hip/hip_runtime.h>

// DeltaNet chunkwise delta rule. b=2,h=8,L=4096,d=128,chunk=32.
// R4: scan gets explicit register double-buffering (prefetch chunk ch+1's
// operands during chunk ch's compute) — R3 was latency-bound (5800 cyc/chunk
// vs ~400 compute, MfmaUtil 0.9%). U-accumulation split into two independent
// MFMA chains. qn stored as bf16 by prep when ws_size permits (84 MB layout),
// else fallback path converts raw q in-register (ws 71.6 MB, proven).

#define Bb 2
#define Hh 8
#define Ll 4096
#define Dd 128
#define DP (Dd + 4)
#define Cc 32
#define CP (Cc + 4)
#define NC (Ll / Cc)       // 128 chunks
#define BHn (Bb * Hh)      // 16 heads

typedef float  f32x16 __attribute__((ext_vector_type(16)));
typedef short  bf16x8 __attribute__((ext_vector_type(8)));

__device__ __forceinline__ short f2bf(float x) {
    union { float f; unsigned u; } a; a.f = x;
    const unsigned r = a.u + 0x7FFFu + ((a.u >> 16) & 1u);  // RNE
    return (short)(r >> 16);
}

// ---------------------------------------------------------------------------
// Kernel 1: per-(head,chunk) precompute. 2048 blocks x 256.
// Outputs: wsU fp32, wsNq fp32, wsWb=-w bf16, wsKtb=kn^T bf16, wsAttnb bf16,
// and (QNB only) wsQnb = qn bf16.
// ---------------------------------------------------------------------------
template <bool QNB>
__global__ __launch_bounds__(256) void prep_kernel(
    const float* __restrict__ q, const float* __restrict__ k,
    const float* __restrict__ v, const float* __restrict__ beta,
    float* __restrict__ wsU, float* __restrict__ wsNq,
    short* __restrict__ wsWb, short* __restrict__ wsKtb,
    short* __restrict__ wsAttnb, short* __restrict__ wsQnb)
{
    __shared__ float sK[Cc][DP];
    __shared__ float sQ[Cc][DP];
    __shared__ float sV[Cc][DP];
    __shared__ float sA[Cc][CP];
    __shared__ float sInv[Cc][CP];
    __shared__ float sBeta[Cc], sNk[Cc], sNq[Cc];

    const int tid = threadIdx.x;
    const int blk = blockIdx.x;          // bh*NC + ch
    const int bh = blk / NC;
    const int ch = blk % NC;
    const size_t base = (size_t)(bh * Ll + ch * Cc) * Dd;

    for (int e = tid; e < Cc * Dd / 4; e += 256) {
        const int r = e >> 5, c4 = e & 31;
        ((float4*)&sQ[r][0])[c4] = ((const float4*)(q + base))[e];
        ((float4*)&sK[r][0])[c4] = ((const float4*)(k + base))[e];
        ((float4*)&sV[r][0])[c4] = ((const float4*)(v + base))[e];
    }
    if (tid < Cc) sBeta[tid] = beta[bh * Ll + ch * Cc + tid];
    __syncthreads();

    // row norms: 4 lanes per row, rows 0..31 = k, 32..63 = q
    {
        const int row = tid >> 2, part = tid & 3;
        const float* src = (row < Cc) ? &sK[row][0] : &sQ[row - Cc][0];
        float s = 0.f;
        #pragma unroll
        for (int j = 0; j < 8; ++j) {
            const float4 t = ((const float4*)src)[part + j * 4];
            s += t.x * t.x + t.y * t.y + t.z * t.z + t.w * t.w;
        }
        s += __shfl_xor(s, 1);
        s += __shfl_xor(s, 2);
        if (part == 0) {
            const float r = 1.0f / sqrtf(s);
            if (row < Cc) sNk[row] = r; else sNq[row - Cc] = r;
        }
    }
    __syncthreads();

    if (tid < Cc) wsNq[bh * Ll + ch * Cc + tid] = sNq[tid];

    for (int e = tid; e < Cc * Dd / 4; e += 256) {
        const int r = e >> 5, c4 = e & 31;
        float4 kk = ((float4*)&sK[r][0])[c4];
        float4 qq = ((float4*)&sQ[r][0])[c4];
        float4 vv = ((float4*)&sV[r][0])[c4];
        const float nk = sNk[r], nq = sNq[r], bb = sBeta[r];
        kk.x *= nk; kk.y *= nk; kk.z *= nk; kk.w *= nk;
        qq.x *= nq; qq.y *= nq; qq.z *= nq; qq.w *= nq;
        vv.x *= bb; vv.y *= bb; vv.z *= bb; vv.w *= bb;
        ((float4*)&sK[r][0])[c4] = kk;
        ((float4*)&sQ[r][0])[c4] = qq;
        ((float4*)&sV[r][0])[c4] = vv;
    }
    __syncthreads();

    // A[i][j] = beta_i * dot(kn_i, kn_j); sInv = I
    for (int e = tid; e < Cc * Cc; e += 256) {
        const int i = e >> 5, j = e & 31;
        const float4* ri = (const float4*)&sK[i][0];
        const float4* rj = (const float4*)&sK[j][0];
        float s = 0.f;
        for (int x = 0; x < Dd / 4; ++x) {
            const float4 a = ri[x], b = rj[x];
            s += a.x * b.x + a.y * b.y + a.z * b.z + a.w * b.w;
        }
        sA[i][j] = s * sBeta[i];
        sInv[i][j] = (i == j) ? 1.0f : 0.0f;
    }
    __syncthreads();

    // forward substitution (unit lower triangular inverse)
    for (int i = 1; i < Cc; ++i) {
        if (tid < i) {
            const int j = tid;
            float s = 0.f;
            for (int m = j; m < i; ++m) s += sA[i][m] * sInv[m][j];
            sInv[i][j] = -s;
        }
        __syncthreads();
    }

    // u = inv @ (v*beta) fp32 ; wsWb = -(inv @ (kn*beta)) bf16
    const size_t cbase = (size_t)blk * Cc * Dd;
    for (int e = tid; e < Cc * Dd; e += 256) {
        const int c = e >> 7, dd = e & 127;
        float su = 0.f, sw = 0.f;
        for (int f = 0; f <= c; ++f) {
            const float iv = sInv[c][f];
            su += iv * sV[f][dd];
            sw += iv * sBeta[f] * sK[f][dd];
        }
        wsU[cbase + e] = su;
        wsWb[cbase + e] = f2bf(-sw);
    }

    // wsKtb[dd][c] = kn[c][dd]
    for (int e = tid; e < Cc * Dd; e += 256) {
        const int dd = e >> 5, cc = e & 31;
        wsKtb[cbase + e] = f2bf(sK[cc][dd]);
    }

    // qn bf16 (fast path only)
    if (QNB) {
        for (int e = tid; e < Cc * Dd; e += 256) {
            const int c = e >> 7, dd = e & 127;
            wsQnb[cbase + e] = f2bf(sQ[c][dd]);
        }
    }

    // attn = tril(qn @ kn^T)  (bf16)
    const size_t abase = (size_t)blk * Cc * Cc;
    for (int e = tid; e < Cc * Cc; e += 256) {
        const int i = e >> 5, j = e & 31;
        float s = 0.f;
        if (j <= i) {
            const float4* ri = (const float4*)&sQ[i][0];
            const float4* rj = (const float4*)&sK[j][0];
            for (int x = 0; x < Dd / 4; ++x) {
                const float4 a = ri[x], b = rj[x];
                s += a.x * b.x + a.y * b.y + a.z * b.z + a.w * b.w;
            }
        }
        wsAttnb[abase + e] = f2bf(s);
    }
}

// ---------------------------------------------------------------------------
// Kernel 2: MFMA scan, register double-buffered.
// Grid (16 heads, 4 col-groups) x 64 threads (1 wave).
// ---------------------------------------------------------------------------
struct Ops {
    bf16x8 wA[8], kA[8], atA[2];
    f32x16 U;
    bf16x8 qa[8];     // QNB path
    float4 qr[16];    // raw-q path
    float  rq;        // raw-q path
};

template <bool QNB>
__device__ __forceinline__ void load_ops(
    Ops& B, int bh, int ch, int colBase, int c, int h,
    const float* __restrict__ q, const short* __restrict__ wsQnb,
    const short* __restrict__ wsWb, const short* __restrict__ wsKtb,
    const short* __restrict__ wsAttnb, const float* __restrict__ wsU,
    const float* __restrict__ wsNq)
{
    const size_t cb = (size_t)(bh * NC + ch) * (Cc * Dd);
    const size_t ab = (size_t)(bh * NC + ch) * (Cc * Cc);
    #pragma unroll
    for (int ks = 0; ks < 8; ++ks)
        B.wA[ks] = ((const bf16x8*)(wsWb + cb))[c * 16 + 2 * ks + h];
    if constexpr (QNB) {
        #pragma unroll
        for (int ks = 0; ks < 8; ++ks)
            B.qa[ks] = ((const bf16x8*)(wsQnb + cb))[c * 16 + 2 * ks + h];
    } else {
        const size_t qb = (size_t)(bh * Ll + ch * Cc) * Dd;
        B.rq = wsNq[bh * Ll + ch * Cc + c];
        #pragma unroll
        for (int ks = 0; ks < 8; ++ks) {
            B.qr[2 * ks]     = ((const float4*)(q + qb))[c * 32 + 4 * ks + 2 * h];
            B.qr[2 * ks + 1] = ((const float4*)(q + qb))[c * 32 + 4 * ks + 2 * h + 1];
        }
    }
    #pragma unroll
    for (int t = 0; t < 4; ++t)
        #pragma unroll
        for (int m = 0; m < 2; ++m)
            B.kA[t * 2 + m] =
                ((const bf16x8*)(wsKtb + cb))[(32 * t + c) * 4 + 2 * m + h];
    B.atA[0] = ((const bf16x8*)(wsAttnb + ab))[c * 4 + h];
    B.atA[1] = ((const bf16x8*)(wsAttnb + ab))[c * 4 + 2 + h];
    #pragma unroll
    for (int r = 0; r < 16; ++r) {
        const int row = (r & 3) + 8 * (r >> 2) + 4 * h;
        B.U[r] = wsU[cb + (size_t)row * Dd + colBase + c];
    }
}

template <bool QNB>
__device__ __forceinline__ void compute_chunk(
    const Ops& B, int bh, int ch, int colBase, int c, int h,
    f32x16& S0, f32x16& S1, f32x16& S2, f32x16& S3, float* __restrict__ out)
{
    bf16x8 qa[8];
    if constexpr (QNB) {
        #pragma unroll
        for (int ks = 0; ks < 8; ++ks) qa[ks] = B.qa[ks];
    } else {
        const float rq = B.rq;
        #pragma unroll
        for (int ks = 0; ks < 8; ++ks) {
            const float4 a = B.qr[2 * ks], b = B.qr[2 * ks + 1];
            qa[ks][0] = f2bf(a.x * rq); qa[ks][1] = f2bf(a.y * rq);
            qa[ks][2] = f2bf(a.z * rq); qa[ks][3] = f2bf(a.w * rq);
            qa[ks][4] = f2bf(b.x * rq); qa[ks][5] = f2bf(b.y * rq);
            qa[ks][6] = f2bf(b.z * rq); qa[ks][7] = f2bf(b.w * rq);
        }
    }

    f32x16 U1 = B.U, U2, O;
    #pragma unroll
    for (int r = 0; r < 16; ++r) { U2[r] = 0.f; O[r] = 0.f; }

    // U1/U2: two independent MFMA chains (halves the serial latency chain)
    #pragma unroll
    for (int ks = 0; ks < 8; ++ks) {
        const f32x16& T = (ks < 2) ? S0 : (ks < 4) ? S1 : (ks < 6) ? S2 : S3;
        const int m = ks & 1;
        bf16x8 sB;   // C-layout -> B-operand via shfl_xor(.,32)
        #pragma unroll
        for (int i = 0; i < 4; ++i) {
            const float A = T[8 * m + i];
            const float Bv = T[8 * m + 4 + i];
            const float z = h ? A : Bv;
            const float rr = __shfl_xor(z, 32);
            sB[i]     = f2bf(h ? rr : A);
            sB[4 + i] = f2bf(h ? Bv : rr);
        }
        if (ks < 4)
            U1 = __builtin_amdgcn_mfma_f32_32x32x16_bf16(B.wA[ks], sB, U1, 0, 0, 0);
        else
            U2 = __builtin_amdgcn_mfma_f32_32x32x16_bf16(B.wA[ks], sB, U2, 0, 0, 0);
        O = __builtin_amdgcn_mfma_f32_32x32x16_bf16(qa[ks], sB, O, 0, 0, 0);
    }

    f32x16 U;
    #pragma unroll
    for (int r = 0; r < 16; ++r) U[r] = U1[r] + U2[r];

    bf16x8 uB[2];
    #pragma unroll
    for (int m = 0; m < 2; ++m) {
        #pragma unroll
        for (int i = 0; i < 4; ++i) {
            const float A = U[8 * m + i];
            const float Bv = U[8 * m + 4 + i];
            const float z = h ? A : Bv;
            const float rr = __shfl_xor(z, 32);
            uB[m][i]     = f2bf(h ? rr : A);
            uB[m][4 + i] = f2bf(h ? Bv : rr);
        }
    }
    O = __builtin_amdgcn_mfma_f32_32x32x16_bf16(B.atA[0], uB[0], O, 0, 0, 0);
    O = __builtin_amdgcn_mfma_f32_32x32x16_bf16(B.atA[1], uB[1], O, 0, 0, 0);

    const size_t qb = (size_t)(bh * Ll + ch * Cc) * Dd;
    #pragma unroll
    for (int r = 0; r < 16; ++r) {
        const int row = (r & 3) + 8 * (r >> 2) + 4 * h;
        out[qb + (size_t)row * Dd + colBase + c] = O[r];
    }

    S0 = __builtin_amdgcn_mfma_f32_32x32x16_bf16(B.kA[0], uB[0], S0, 0, 0, 0);
    S0 = __builtin_amdgcn_mfma_f32_32x32x16_bf16(B.kA[1], uB[1], S0, 0, 0, 0);
    S1 = __builtin_amdgcn_mfma_f32_32x32x16_bf16(B.kA[2], uB[0], S1, 0, 0, 0);
    S1 = __builtin_amdgcn_mfma_f32_32x32x16_bf16(B.kA[3], uB[1], S1, 0, 0, 0);
    S2 = __builtin_amdgcn_mfma_f32_32x32x16_bf16(B.kA[4], uB[0], S2, 0, 0, 0);
    S2 = __builtin_amdgcn_mfma_f32_32x32x16_bf16(B.kA[5], uB[1], S2, 0, 0, 0);
    S3 = __builtin_amdgcn_mfma_f32_32x32x16_bf16(B.kA[6], uB[0], S3, 0, 0, 0);
    S3 = __builtin_amdgcn_mfma_f32_32x32x16_bf16(B.kA[7], uB[1], S3, 0, 0, 0);
}

template <bool QNB>
__global__ __launch_bounds__(64, 1) void scan_kernel(
    const float* __restrict__ q, const float* __restrict__ wsU,
    const short* __restrict__ wsWb, const short* __restrict__ wsKtb,
    const short* __restrict__ wsAttnb, const short* __restrict__ wsQnb,
    const float* __restrict__ wsNq, float* __restrict__ out)
{
    const int lane = threadIdx.x;
    const int h = lane >> 5;
    const int c = lane & 31;
    const int bh = blockIdx.x;
    const int colBase = blockIdx.y * 32;

    f32x16 S0, S1, S2, S3;
    #pragma unroll
    for (int r = 0; r < 16; ++r) { S0[r]=0.f; S1[r]=0.f; S2[r]=0.f; S3[r]=0.f; }

    Ops A, B;
    load_ops<QNB>(A, bh, 0, colBase, c, h, q, wsQnb, wsWb, wsKtb, wsAttnb,
                  wsU, wsNq);
    for (int ch = 0; ch < NC; ch += 2) {
        load_ops<QNB>(B, bh, ch + 1, colBase, c, h, q, wsQnb, wsWb, wsKtb,
                      wsAttnb, wsU, wsNq);
        compute_chunk<QNB>(A, bh, ch, colBase, c, h, S0, S1, S2, S3, out);
        load_ops<QNB>(A, bh, (ch + 2 < NC) ? ch + 2 : ch, colBase, c, h, q,
                      wsQnb, wsWb, wsKtb, wsAttnb, wsU, wsNq);
        compute_chunk<QNB>(B, bh, ch + 1, colBase, c, h, S0, S1, S2, S3, out);
    }

    // S_final -> d_out tail
    const size_t soff = (size_t)Bb * Hh * Ll * Dd;
    #pragma unroll
    for (int t = 0; t < 4; ++t) {
        const f32x16& T = (t == 0) ? S0 : (t == 1) ? S1 : (t == 2) ? S2 : S3;
        #pragma unroll
        for (int r = 0; r < 16; ++r) {
            const int row = 32 * t + (r & 3) + 8 * (r >> 2) + 4 * h;
            out[soff + (size_t)bh * Dd * Dd + (size_t)row * Dd + colBase + c] =
                T[r];
        }
    }
}

extern "C" void kernel_launch(void* const* d_in, const int* in_sizes, int n_in,
                              void* d_out, int out_size, void* d_ws,
                              size_t ws_size, hipStream_t stream) {
    const float* q    = (const float*)d_in[0];
    const float* k    = (const float*)d_in[1];
    const float* v    = (const float*)d_in[2];
    const float* beta = (const float*)d_in[3];
    float* out = (float*)d_out;

    const size_t nQK = (size_t)BHn * Ll * Dd;          // 8,388,608
    float* wsU    = (float*)d_ws;                      // fp32, 32 MB
    float* wsNq   = wsU + nQK;                         // fp32, 0.25 MB
    short* wsWb   = (short*)(wsNq + (size_t)BHn * Ll); // bf16, 16 MB
    short* wsKtb  = wsWb + nQK;                        // bf16, 16 MB
    short* wsAttnb = wsKtb + nQK;                      // bf16, 4 MB
    short* wsQnb  = wsAttnb + (size_t)BHn * NC * Cc * Cc; // bf16, 16 MB (opt)
    const size_t need_qnb = (size_t)((char*)(wsQnb + nQK) - (char*)d_ws);

    if (ws_size >= need_qnb) {
        prep_kernel<true><<<dim3(BHn * NC), 256, 0, stream>>>(
            q, k, v, beta, wsU, wsNq, wsWb, wsKtb, wsAttnb, wsQnb);
        scan_kernel<true><<<dim3(BHn, 4), 64, 0, stream>>>(
            q, wsU, wsWb, wsKtb, wsAttnb, wsQnb, wsNq, out);
    } else {
        prep_kernel<false><<<dim3(BHn * NC), 256, 0, stream>>>(
            q, k, v, beta, wsU, wsNq, wsWb, wsKtb, wsAttnb, wsQnb);
        scan_kernel<false><<<dim3(BHn, 4), 64, 0, stream>>>(
            q, wsU, wsWb, wsKtb, wsAttnb, wsQnb, wsNq, out);
    }
}